// Round 1
// baseline (14671.518 us; speedup 1.0000x reference)
//
#include <hip/hip_runtime.h>
#include <hip/hip_bf16.h>
#include <cstddef>

#define DIMK 512
#define HEADS 8
#define DHEAD 64
#define NSEQ 2048
#define NB 8
#define M_TOT (NB * NSEQ)   // 16384

// ---------------------------------------------------------------------------
// GEMM 1: qkv = x @ w_qkv  (M=16384, K=512, N=1536), epilogue scatters into
// Q/K/V with layout [b*H + h][n][d] so attention reads are contiguous in d.
// ---------------------------------------------------------------------------
__global__ __launch_bounds__(256) void gemm_qkv(
    const float* __restrict__ X, const float* __restrict__ W,
    float* __restrict__ Q, float* __restrict__ Kd, float* __restrict__ Vd)
{
    __shared__ float As[16][65];   // A^T tile, +1 pad
    __shared__ float Bs[16][65];
    const int tid  = threadIdx.x;
    const int row0 = blockIdx.y * 64;
    const int col0 = blockIdx.x * 64;
    const int tx = tid & 15, ty = tid >> 4;
    float acc[4][4] = {};
    for (int k0 = 0; k0 < DIMK; k0 += 16) {
        {
            const int r = tid >> 2, c = (tid & 3) << 2;
            const float4 a = *(const float4*)(X + (size_t)(row0 + r) * DIMK + k0 + c);
            As[c + 0][r] = a.x; As[c + 1][r] = a.y;
            As[c + 2][r] = a.z; As[c + 3][r] = a.w;
        }
        {
            const int r = tid >> 4, c = (tid & 15) << 2;
            const float4 b4 = *(const float4*)(W + (size_t)(k0 + r) * 1536 + col0 + c);
            Bs[r][c + 0] = b4.x; Bs[r][c + 1] = b4.y;
            Bs[r][c + 2] = b4.z; Bs[r][c + 3] = b4.w;
        }
        __syncthreads();
        #pragma unroll
        for (int kk = 0; kk < 16; ++kk) {
            float a[4], b[4];
            #pragma unroll
            for (int i = 0; i < 4; ++i) a[i] = As[kk][ty * 4 + i];
            #pragma unroll
            for (int j = 0; j < 4; ++j) b[j] = Bs[kk][tx * 4 + j];
            #pragma unroll
            for (int i = 0; i < 4; ++i)
                #pragma unroll
                for (int j = 0; j < 4; ++j) acc[i][j] = fmaf(a[i], b[j], acc[i][j]);
        }
        __syncthreads();
    }
    #pragma unroll
    for (int i = 0; i < 4; ++i) {
        const int gr = row0 + ty * 4 + i;
        const int bb = gr >> 11, n = gr & 2047;
        #pragma unroll
        for (int j = 0; j < 4; ++j) {
            const int gc = col0 + tx * 4 + j;
            const int which = gc >> 9, w = gc & 511;
            const int h = w >> 6, d = w & 63;
            float* dst = (which == 0) ? Q : (which == 1 ? Kd : Vd);
            dst[(((size_t)(bb * HEADS + h)) * NSEQ + n) * DHEAD + d] = acc[i][j];
        }
    }
}

// ---------------------------------------------------------------------------
// Attention: one block (256 thr) per (bh, query i). Logits for all 2048 keys
// live in LDS; block reductions for max and sum; self-token masked out.
// Output written as [b][n][h*64+d] so the out-projection GEMM reads row-major.
// ---------------------------------------------------------------------------
__global__ __launch_bounds__(256) void attn_kernel(
    const float* __restrict__ Q, const float* __restrict__ Kd,
    const float* __restrict__ Vd, const float* __restrict__ log_scale,
    float* __restrict__ O)
{
    __shared__ float p[NSEQ];
    __shared__ float red[256];
    __shared__ float qs[DHEAD];
    const int bh  = blockIdx.y;   // 0..63
    const int i   = blockIdx.x;   // 0..2047
    const int tid = threadIdx.x;
    const float scale = __expf(log_scale[0]);

    if (tid < DHEAD) qs[tid] = Q[((size_t)bh * NSEQ + i) * DHEAD + tid];
    __syncthreads();

    // ---- logits ----
    float lmax = -3.4e38f;
    for (int j = tid; j < NSEQ; j += 256) {
        const float* krow = Kd + ((size_t)bh * NSEQ + j) * DHEAD;
        float s = 0.f;
        #pragma unroll
        for (int d = 0; d < DHEAD; d += 4) {
            const float4 kv = *(const float4*)(krow + d);
            s += qs[d] * kv.x + qs[d + 1] * kv.y + qs[d + 2] * kv.z + qs[d + 3] * kv.w;
        }
        s *= scale;
        if (j == i) s = -3.4e38f;   // exclude self token
        p[j] = s;
        lmax = fmaxf(lmax, s);
    }
    red[tid] = lmax;
    __syncthreads();
    for (int off = 128; off > 0; off >>= 1) {
        if (tid < off) red[tid] = fmaxf(red[tid], red[tid + off]);
        __syncthreads();
    }
    const float m = red[0];
    __syncthreads();   // all lanes have read red[0] before it is overwritten

    // ---- exp + sum ----
    float lsum = 0.f;
    for (int j = tid; j < NSEQ; j += 256) {
        const float e = __expf(p[j] - m);   // masked entry underflows to 0
        p[j] = e;
        lsum += e;
    }
    red[tid] = lsum;
    __syncthreads();
    for (int off = 128; off > 0; off >>= 1) {
        if (tid < off) red[tid] += red[tid + off];
        __syncthreads();
    }
    const float inv = 1.0f / red[0];

    // ---- PV: thread = (chunk, d); coalesced V reads across d ----
    const int d = tid & 63, chunk = tid >> 6;
    float acc = 0.f;
    const float* vbase = Vd + (size_t)bh * NSEQ * DHEAD;
    for (int j = chunk * 512; j < chunk * 512 + 512; ++j)
        acc = fmaf(p[j], vbase[(size_t)j * DHEAD + d], acc);
    __syncthreads();   // red[0] reads done before overwrite
    red[tid] = acc;
    __syncthreads();
    if (tid < DHEAD) {
        const float o = (red[tid] + red[tid + 64] + red[tid + 128] + red[tid + 192]) * inv;
        const int bb = bh >> 3, h = bh & 7;
        O[((size_t)(bb * NSEQ + i)) * 512 + h * 64 + d] = o;
    }
}

// ---------------------------------------------------------------------------
// GEMM 2: out = O @ w_out + b_out  (M=16384, K=512, N=512)
// ---------------------------------------------------------------------------
__global__ __launch_bounds__(256) void gemm_out(
    const float* __restrict__ A, const float* __restrict__ W,
    const float* __restrict__ bias, float* __restrict__ C)
{
    __shared__ float As[16][65];
    __shared__ float Bs[16][65];
    const int tid  = threadIdx.x;
    const int row0 = blockIdx.y * 64;
    const int col0 = blockIdx.x * 64;
    const int tx = tid & 15, ty = tid >> 4;
    float acc[4][4] = {};
    for (int k0 = 0; k0 < DIMK; k0 += 16) {
        {
            const int r = tid >> 2, c = (tid & 3) << 2;
            const float4 a = *(const float4*)(A + (size_t)(row0 + r) * DIMK + k0 + c);
            As[c + 0][r] = a.x; As[c + 1][r] = a.y;
            As[c + 2][r] = a.z; As[c + 3][r] = a.w;
        }
        {
            const int r = tid >> 4, c = (tid & 15) << 2;
            const float4 b4 = *(const float4*)(W + (size_t)(k0 + r) * 512 + col0 + c);
            Bs[r][c + 0] = b4.x; Bs[r][c + 1] = b4.y;
            Bs[r][c + 2] = b4.z; Bs[r][c + 3] = b4.w;
        }
        __syncthreads();
        #pragma unroll
        for (int kk = 0; kk < 16; ++kk) {
            float a[4], b[4];
            #pragma unroll
            for (int i = 0; i < 4; ++i) a[i] = As[kk][ty * 4 + i];
            #pragma unroll
            for (int j = 0; j < 4; ++j) b[j] = Bs[kk][tx * 4 + j];
            #pragma unroll
            for (int i = 0; i < 4; ++i)
                #pragma unroll
                for (int j = 0; j < 4; ++j) acc[i][j] = fmaf(a[i], b[j], acc[i][j]);
        }
        __syncthreads();
    }
    #pragma unroll
    for (int i = 0; i < 4; ++i) {
        const int gr = row0 + ty * 4 + i;
        #pragma unroll
        for (int j = 0; j < 4; ++j) {
            const int gc = col0 + tx * 4 + j;
            C[(size_t)gr * 512 + gc] = acc[i][j] + bias[gc];
        }
    }
}

extern "C" void kernel_launch(void* const* d_in, const int* in_sizes, int n_in,
                              void* d_out, int out_size, void* d_ws, size_t ws_size,
                              hipStream_t stream) {
    const float* x         = (const float*)d_in[0];
    const float* w_qkv     = (const float*)d_in[1];
    const float* w_out     = (const float*)d_in[2];
    const float* b_out     = (const float*)d_in[3];
    const float* log_scale = (const float*)d_in[4];
    float* out = (float*)d_out;

    float* ws = (float*)d_ws;
    const size_t SZ = (size_t)NB * HEADS * NSEQ * DHEAD;   // 8,388,608 floats
    float* Q  = ws;
    float* Kd = ws + SZ;
    float* Vd = ws + 2 * SZ;
    float* O  = ws + 3 * SZ;   // total 134.2 MB

    dim3 g1(1536 / 64, M_TOT / 64);
    gemm_qkv<<<g1, 256, 0, stream>>>(x, w_qkv, Q, Kd, Vd);

    dim3 g2(NSEQ, NB * HEADS);
    attn_kernel<<<g2, 256, 0, stream>>>(Q, Kd, Vd, log_scale, O);

    dim3 g3(512 / 64, M_TOT / 64);
    gemm_out<<<g3, 256, 0, stream>>>(O, w_out, b_out, out);
}

// Round 2
// 953.999 us; speedup vs baseline: 15.3790x; 15.3790x over previous
//
#include <hip/hip_runtime.h>
#include <hip/hip_bf16.h>
#include <cstddef>

#define DIMK 512
#define HEADS 8
#define DHEAD 64
#define NSEQ 2048
#define NB 8
#define M_TOT (NB * NSEQ)   // 16384

typedef __attribute__((ext_vector_type(8))) short bf16x8;
typedef __attribute__((ext_vector_type(4))) float f32x4;

__device__ __forceinline__ unsigned short f2bf(float f) {
    union { float f; unsigned int u; } v; v.f = f;
    unsigned int r = v.u + 0x7fffu + ((v.u >> 16) & 1u);   // round-nearest-even
    return (unsigned short)(r >> 16);
}

// ---------------------------------------------------------------------------
// GEMM 1: qkv = x @ w_qkv (fp32 compute). Epilogue emits:
//   Qb  bf16 [bh][n][d]  (pre-scaled by exp(log_scale))
//   Kb  bf16 [bh][n][d]
//   VTb bf16 [bh][d][n]  (transposed for PV B-fragment reads)
// `which` (Q/K/V) is uniform per block: blockIdx.x 0-7 -> Q, 8-15 -> K, 16-23 -> V.
// ---------------------------------------------------------------------------
__global__ __launch_bounds__(256) void gemm_qkv(
    const float* __restrict__ X, const float* __restrict__ W,
    const float* __restrict__ log_scale,
    unsigned short* __restrict__ Qb, unsigned short* __restrict__ Kb,
    unsigned short* __restrict__ VTb)
{
    __shared__ float As[16][65];
    __shared__ float Bs[16][65];
    const int tid  = threadIdx.x;
    const int row0 = blockIdx.y * 64;
    const int col0 = blockIdx.x * 64;
    const int tx = tid & 15, ty = tid >> 4;
    float acc[4][4] = {};
    for (int k0 = 0; k0 < DIMK; k0 += 16) {
        {
            const int r = tid >> 2, c = (tid & 3) << 2;
            const float4 a = *(const float4*)(X + (size_t)(row0 + r) * DIMK + k0 + c);
            As[c + 0][r] = a.x; As[c + 1][r] = a.y;
            As[c + 2][r] = a.z; As[c + 3][r] = a.w;
        }
        {
            const int r = tid >> 4, c = (tid & 15) << 2;
            const float4 b4 = *(const float4*)(W + (size_t)(k0 + r) * 1536 + col0 + c);
            Bs[r][c + 0] = b4.x; Bs[r][c + 1] = b4.y;
            Bs[r][c + 2] = b4.z; Bs[r][c + 3] = b4.w;
        }
        __syncthreads();
        #pragma unroll
        for (int kk = 0; kk < 16; ++kk) {
            float a[4], b[4];
            #pragma unroll
            for (int i = 0; i < 4; ++i) a[i] = As[kk][ty * 4 + i];
            #pragma unroll
            for (int j = 0; j < 4; ++j) b[j] = Bs[kk][tx * 4 + j];
            #pragma unroll
            for (int i = 0; i < 4; ++i)
                #pragma unroll
                for (int j = 0; j < 4; ++j) acc[i][j] = fmaf(a[i], b[j], acc[i][j]);
        }
        __syncthreads();
    }
    const int which = blockIdx.x >> 3;            // 0=Q 1=K 2=V (uniform per block)
    const float scale = __expf(log_scale[0]);
    #pragma unroll
    for (int i = 0; i < 4; ++i) {
        const int gr = row0 + ty * 4 + i;
        const int bb = gr >> 11, n = gr & 2047;
        #pragma unroll
        for (int j = 0; j < 4; ++j) {
            const int lc = ((blockIdx.x & 7) << 6) + tx * 4 + j;   // 0..511
            const int h = lc >> 6, d = lc & 63;
            const size_t bh = (size_t)(bb * HEADS + h);
            if (which == 0)
                Qb[(bh * NSEQ + n) * DHEAD + d] = f2bf(acc[i][j] * scale);
            else if (which == 1)
                Kb[(bh * NSEQ + n) * DHEAD + d] = f2bf(acc[i][j]);
            else
                VTb[(bh * DHEAD + d) * NSEQ + n] = f2bf(acc[i][j]);
        }
    }
}

// ---------------------------------------------------------------------------
// Flash-style MFMA attention. Block = 256 thr = 4 waves; wave w owns 16 query
// rows (block covers 64). Loop over key-tiles of 64: stage K-tile [64][64] and
// V^T-tile [64 d][64 keys] in LDS (+8 bf16 pad), QK^T via 8 mfma 16x16x32,
// online softmax (16-lane butterflies), P -> LDS (C-layout -> A-layout), PV
// via 8 mfma. Output O fp32 [b][n][h*64+d] for the fp32 out-projection.
// ---------------------------------------------------------------------------
__global__ __launch_bounds__(256) void attn_mfma(
    const unsigned short* __restrict__ Qb, const unsigned short* __restrict__ Kb,
    const unsigned short* __restrict__ VTb, float* __restrict__ O)
{
    __shared__ __align__(16) unsigned short Ks[64][72];
    __shared__ __align__(16) unsigned short Vs[64][72];   // V^T tile: [d][key]
    __shared__ __align__(16) unsigned short Ps[4][16][72];

    const int tid  = threadIdx.x;
    const int wave = tid >> 6;
    const int lane = tid & 63;
    const int l16  = lane & 15;
    const int quad = lane >> 4;
    const int bh   = blockIdx.y;
    const int qw   = blockIdx.x * 64 + wave * 16;   // wave's query base

    const unsigned short* Qg = Qb  + (size_t)bh * NSEQ * DHEAD;
    const unsigned short* Kg = Kb  + (size_t)bh * NSEQ * DHEAD;
    const unsigned short* Vg = VTb + (size_t)bh * DHEAD * NSEQ;

    // Q A-fragments, resident all kernel: A[m=l16][k=chunk*32+quad*8+j]
    bf16x8 a_q0 = *(const bf16x8*)(Qg + (size_t)(qw + l16) * DHEAD + quad * 8);
    bf16x8 a_q1 = *(const bf16x8*)(Qg + (size_t)(qw + l16) * DHEAD + 32 + quad * 8);

    f32x4 o_acc[4];
    #pragma unroll
    for (int t = 0; t < 4; ++t) o_acc[t] = (f32x4){0.f, 0.f, 0.f, 0.f};
    float m_r[4], l_r[4];
    #pragma unroll
    for (int r = 0; r < 4; ++r) { m_r[r] = -3.0e38f; l_r[r] = 0.f; }

    for (int j0 = 0; j0 < NSEQ; j0 += 64) {
        __syncthreads();   // everyone done reading Ks/Vs/Ps from prev iter
        {
            const int r  = tid >> 3;          // 0..31
            const int cc = (tid & 7) * 8;
            *(bf16x8*)(&Ks[r][cc])      = *(const bf16x8*)(Kg + (size_t)(j0 + r) * DHEAD + cc);
            *(bf16x8*)(&Ks[r + 32][cc]) = *(const bf16x8*)(Kg + (size_t)(j0 + r + 32) * DHEAD + cc);
            *(bf16x8*)(&Vs[r][cc])      = *(const bf16x8*)(Vg + (size_t)r * NSEQ + j0 + cc);
            *(bf16x8*)(&Vs[r + 32][cc]) = *(const bf16x8*)(Vg + (size_t)(r + 32) * NSEQ + j0 + cc);
        }
        __syncthreads();   // tiles staged

        // ---- S = Q K^T (scale already folded into Q) ----
        float sv[4][4];
        #pragma unroll
        for (int t = 0; t < 4; ++t) {
            f32x4 acc = (f32x4){0.f, 0.f, 0.f, 0.f};
            bf16x8 b0 = *(const bf16x8*)(&Ks[t * 16 + l16][quad * 8]);
            bf16x8 b1 = *(const bf16x8*)(&Ks[t * 16 + l16][32 + quad * 8]);
            acc = __builtin_amdgcn_mfma_f32_16x16x32_bf16(a_q0, b0, acc, 0, 0, 0);
            acc = __builtin_amdgcn_mfma_f32_16x16x32_bf16(a_q1, b1, acc, 0, 0, 0);
            const int col = j0 + t * 16 + l16;
            #pragma unroll
            for (int r = 0; r < 4; ++r) {
                float s = acc[r];
                if (qw + quad * 4 + r == col) s = -1.0e30f;   // exclude self token
                sv[t][r] = s;
            }
        }

        // ---- online softmax ----
        float rmax[4];
        #pragma unroll
        for (int r = 0; r < 4; ++r)
            rmax[r] = fmaxf(fmaxf(sv[0][r], sv[1][r]), fmaxf(sv[2][r], sv[3][r]));
        #pragma unroll
        for (int off = 1; off < 16; off <<= 1)
            #pragma unroll
            for (int r = 0; r < 4; ++r)
                rmax[r] = fmaxf(rmax[r], __shfl_xor(rmax[r], off, 64));

        float rsum[4] = {0.f, 0.f, 0.f, 0.f};
        float alpha[4];
        #pragma unroll
        for (int r = 0; r < 4; ++r) {
            const float mnew = fmaxf(m_r[r], rmax[r]);
            alpha[r] = __expf(m_r[r] - mnew);
            m_r[r] = mnew;
        }
        #pragma unroll
        for (int t = 0; t < 4; ++t)
            #pragma unroll
            for (int r = 0; r < 4; ++r) {
                const float p = __expf(sv[t][r] - m_r[r]);
                sv[t][r] = p;
                rsum[r] += p;
            }
        #pragma unroll
        for (int off = 1; off < 16; off <<= 1)
            #pragma unroll
            for (int r = 0; r < 4; ++r)
                rsum[r] += __shfl_xor(rsum[r], off, 64);
        #pragma unroll
        for (int r = 0; r < 4; ++r) l_r[r] = l_r[r] * alpha[r] + rsum[r];
        #pragma unroll
        for (int t = 0; t < 4; ++t)
            #pragma unroll
            for (int r = 0; r < 4; ++r) o_acc[t][r] *= alpha[r];

        // ---- P: C-layout -> LDS -> A-layout ----
        #pragma unroll
        for (int t = 0; t < 4; ++t)
            #pragma unroll
            for (int r = 0; r < 4; ++r)
                Ps[wave][quad * 4 + r][t * 16 + l16] = f2bf(sv[t][r]);
        __syncthreads();   // Ps visible (also orders vs. next restage)

        bf16x8 a_p0 = *(const bf16x8*)(&Ps[wave][l16][quad * 8]);
        bf16x8 a_p1 = *(const bf16x8*)(&Ps[wave][l16][32 + quad * 8]);

        // ---- O += P V : B[k=key][n=d] read from V^T tile rows ----
        #pragma unroll
        for (int t = 0; t < 4; ++t) {
            bf16x8 b0 = *(const bf16x8*)(&Vs[t * 16 + l16][quad * 8]);
            bf16x8 b1 = *(const bf16x8*)(&Vs[t * 16 + l16][32 + quad * 8]);
            o_acc[t] = __builtin_amdgcn_mfma_f32_16x16x32_bf16(a_p0, b0, o_acc[t], 0, 0, 0);
            o_acc[t] = __builtin_amdgcn_mfma_f32_16x16x32_bf16(a_p1, b1, o_acc[t], 0, 0, 0);
        }
    }

    // ---- epilogue: O[b][n][h*64+d] = o_acc / l ----
    const int bb = bh >> 3, h = bh & 7;
    #pragma unroll
    for (int r = 0; r < 4; ++r) {
        const int n = qw + quad * 4 + r;
        const float inv = 1.0f / l_r[r];
        #pragma unroll
        for (int t = 0; t < 4; ++t) {
            const int d = t * 16 + l16;
            O[((size_t)(bb * NSEQ + n)) * 512 + h * 64 + d] = o_acc[t][r] * inv;
        }
    }
}

// ---------------------------------------------------------------------------
// GEMM 2: out = O @ w_out + b_out  (fp32, M=16384, K=512, N=512)
// ---------------------------------------------------------------------------
__global__ __launch_bounds__(256) void gemm_out(
    const float* __restrict__ A, const float* __restrict__ W,
    const float* __restrict__ bias, float* __restrict__ C)
{
    __shared__ float As[16][65];
    __shared__ float Bs[16][65];
    const int tid  = threadIdx.x;
    const int row0 = blockIdx.y * 64;
    const int col0 = blockIdx.x * 64;
    const int tx = tid & 15, ty = tid >> 4;
    float acc[4][4] = {};
    for (int k0 = 0; k0 < DIMK; k0 += 16) {
        {
            const int r = tid >> 2, c = (tid & 3) << 2;
            const float4 a = *(const float4*)(A + (size_t)(row0 + r) * DIMK + k0 + c);
            As[c + 0][r] = a.x; As[c + 1][r] = a.y;
            As[c + 2][r] = a.z; As[c + 3][r] = a.w;
        }
        {
            const int r = tid >> 4, c = (tid & 15) << 2;
            const float4 b4 = *(const float4*)(W + (size_t)(k0 + r) * 512 + col0 + c);
            Bs[r][c + 0] = b4.x; Bs[r][c + 1] = b4.y;
            Bs[r][c + 2] = b4.z; Bs[r][c + 3] = b4.w;
        }
        __syncthreads();
        #pragma unroll
        for (int kk = 0; kk < 16; ++kk) {
            float a[4], b[4];
            #pragma unroll
            for (int i = 0; i < 4; ++i) a[i] = As[kk][ty * 4 + i];
            #pragma unroll
            for (int j = 0; j < 4; ++j) b[j] = Bs[kk][tx * 4 + j];
            #pragma unroll
            for (int i = 0; i < 4; ++i)
                #pragma unroll
                for (int j = 0; j < 4; ++j) acc[i][j] = fmaf(a[i], b[j], acc[i][j]);
        }
        __syncthreads();
    }
    #pragma unroll
    for (int i = 0; i < 4; ++i) {
        const int gr = row0 + ty * 4 + i;
        #pragma unroll
        for (int j = 0; j < 4; ++j) {
            const int gc = col0 + tx * 4 + j;
            C[(size_t)gr * 512 + gc] = acc[i][j] + bias[gc];
        }
    }
}

extern "C" void kernel_launch(void* const* d_in, const int* in_sizes, int n_in,
                              void* d_out, int out_size, void* d_ws, size_t ws_size,
                              hipStream_t stream) {
    const float* x         = (const float*)d_in[0];
    const float* w_qkv     = (const float*)d_in[1];
    const float* w_out     = (const float*)d_in[2];
    const float* b_out     = (const float*)d_in[3];
    const float* log_scale = (const float*)d_in[4];
    float* out = (float*)d_out;

    char* ws = (char*)d_ws;
    const size_t NQKV = (size_t)NB * HEADS * NSEQ * DHEAD;       // 8,388,608 elems
    unsigned short* Qb  = (unsigned short*)(ws);                  // 16.8 MB
    unsigned short* Kb  = (unsigned short*)(ws + 2 * NQKV);       // 16.8 MB
    unsigned short* VTb = (unsigned short*)(ws + 4 * NQKV);       // 16.8 MB
    float*          Of  = (float*)(ws + 6 * NQKV);                // 33.6 MB

    dim3 g1(1536 / 64, M_TOT / 64);
    gemm_qkv<<<g1, 256, 0, stream>>>(x, w_qkv, log_scale, Qb, Kb, VTb);

    dim3 g2(NSEQ / 64, NB * HEADS);
    attn_mfma<<<g2, 256, 0, stream>>>(Qb, Kb, VTb, Of);

    dim3 g3(512 / 64, M_TOT / 64);
    gemm_out<<<g3, 256, 0, stream>>>(Of, w_out, b_out, out);
}

// Round 3
// 404.126 us; speedup vs baseline: 36.3043x; 2.3606x over previous
//
#include <hip/hip_runtime.h>
#include <hip/hip_bf16.h>
#include <cstddef>

#define DIMK 512
#define HEADS 8
#define DHEAD 64
#define NSEQ 2048
#define NB 8
#define M_TOT (NB * NSEQ)   // 16384

typedef __attribute__((ext_vector_type(8))) short bf16x8;
typedef __attribute__((ext_vector_type(4))) float f32x4;

__device__ __forceinline__ unsigned short f2bf(float f) {
    union { float f; unsigned int u; } v; v.f = f;
    unsigned int r = v.u + 0x7fffu + ((v.u >> 16) & 1u);   // round-nearest-even
    return (unsigned short)(r >> 16);
}

// async 16B/lane global->LDS. LDS dest is wave-uniform base + lane*16.
__device__ __forceinline__ void glds16(const unsigned short* g, unsigned short* l) {
    __builtin_amdgcn_global_load_lds(
        (const __attribute__((address_space(1))) void*)g,
        (__attribute__((address_space(3))) void*)l, 16, 0, 0);
}

// ---------------------------------------------------------------------------
// Pre-pass: x fp32 -> bf16 row-major [m][k]
// ---------------------------------------------------------------------------
__global__ __launch_bounds__(256) void f32_to_bf16(
    const float* __restrict__ in, unsigned short* __restrict__ out)
{
    const size_t i = ((size_t)blockIdx.x * 256 + threadIdx.x) * 8;
    const float4 a = *(const float4*)(in + i);
    const float4 b = *(const float4*)(in + i + 4);
    bf16x8 o;
    o[0] = (short)f2bf(a.x); o[1] = (short)f2bf(a.y);
    o[2] = (short)f2bf(a.z); o[3] = (short)f2bf(a.w);
    o[4] = (short)f2bf(b.x); o[5] = (short)f2bf(b.y);
    o[6] = (short)f2bf(b.z); o[7] = (short)f2bf(b.w);
    *(bf16x8*)(out + i) = o;
}

// ---------------------------------------------------------------------------
// Pre-pass: W [K][N] fp32 -> WT [N][K] bf16; output rows n < nscale get
// *exp(log_scale) folded in (Q-columns of w_qkv).
// ---------------------------------------------------------------------------
__global__ __launch_bounds__(256) void transpose_w(
    const float* __restrict__ W, unsigned short* __restrict__ WT,
    int K, int N, const float* __restrict__ log_scale, int nscale)
{
    __shared__ float t[32][33];
    const int tx = threadIdx.x & 31, ty = threadIdx.x >> 5;   // ty 0..7
    const int k0 = blockIdx.y * 32, n0 = blockIdx.x * 32;
    #pragma unroll
    for (int s = 0; s < 32; s += 8)
        t[ty + s][tx] = W[(size_t)(k0 + ty + s) * N + n0 + tx];
    __syncthreads();
    float sc = 1.0f;
    if (n0 < nscale) sc = __expf(log_scale[0]);
    #pragma unroll
    for (int s = 0; s < 32; s += 8)
        WT[(size_t)(n0 + ty + s) * K + k0 + tx] = f2bf(t[tx][ty + s] * sc);
}

// ---------------------------------------------------------------------------
// MFMA GEMM 1: [16384 x 512] @ [512 x 1536] via A=[m][k] bf16, BT=[n][k] bf16.
// 128x128 tile, BK=32, global_load_lds staging (m97 structure).
// Epilogue scatters Q (bf16, scale pre-folded), K (bf16), V^T (bf16).
// ---------------------------------------------------------------------------
__global__ __launch_bounds__(256) void gemm_qkv_mfma(
    const unsigned short* __restrict__ Xb, const unsigned short* __restrict__ WT,
    unsigned short* __restrict__ Qb, unsigned short* __restrict__ Kb,
    unsigned short* __restrict__ VTb)
{
    __shared__ unsigned short As[128 * 32];
    __shared__ unsigned short Bs[128 * 32];
    const int tid = threadIdx.x, wave = tid >> 6, lane = tid & 63;
    const int l16 = lane & 15, quad = lane >> 4;
    const int m0 = blockIdx.y * 128, col0 = blockIdx.x * 128;
    const int wrow = wave >> 1, wcol = wave & 1;

    unsigned short* lA0 = As + (wave * 16) * 32;
    unsigned short* lA1 = As + (64 + wave * 16) * 32;
    unsigned short* lB0 = Bs + (wave * 16) * 32;
    unsigned short* lB1 = Bs + (64 + wave * 16) * 32;
    const unsigned short* gA = Xb + (size_t)(m0 + wave * 16 + (lane >> 2)) * DIMK + (lane & 3) * 8;
    const unsigned short* gB = WT + (size_t)(col0 + wave * 16 + (lane >> 2)) * DIMK + (lane & 3) * 8;

    f32x4 acc[4][4];
    #pragma unroll
    for (int i = 0; i < 4; ++i)
        #pragma unroll
        for (int j = 0; j < 4; ++j) acc[i][j] = (f32x4){0.f, 0.f, 0.f, 0.f};

    for (int k0 = 0; k0 < DIMK; k0 += 32) {
        __syncthreads();
        glds16(gA + k0, lA0);
        glds16(gA + (size_t)64 * DIMK + k0, lA1);
        glds16(gB + k0, lB0);
        glds16(gB + (size_t)64 * DIMK + k0, lB1);
        __syncthreads();
        bf16x8 af[4], bfr[4];
        #pragma unroll
        for (int i = 0; i < 4; ++i)
            af[i] = *(const bf16x8*)(As + (wrow * 64 + i * 16 + l16) * 32 + quad * 8);
        #pragma unroll
        for (int j = 0; j < 4; ++j)
            bfr[j] = *(const bf16x8*)(Bs + (wcol * 64 + j * 16 + l16) * 32 + quad * 8);
        #pragma unroll
        for (int i = 0; i < 4; ++i)
            #pragma unroll
            for (int j = 0; j < 4; ++j)
                acc[i][j] = __builtin_amdgcn_mfma_f32_16x16x32_bf16(af[i], bfr[j], acc[i][j], 0, 0, 0);
    }

    const int which = blockIdx.x >> 2;   // 0=Q 1=K 2=V, uniform per block
    #pragma unroll
    for (int i = 0; i < 4; ++i) {
        #pragma unroll
        for (int r = 0; r < 4; ++r) {
            const int gr = m0 + wrow * 64 + i * 16 + quad * 4 + r;
            const int bb = gr >> 11, n = gr & 2047;
            #pragma unroll
            for (int j = 0; j < 4; ++j) {
                const int col = col0 + wcol * 64 + j * 16 + l16;
                const int w = col & 511, h = w >> 6, d = w & 63;
                const size_t bh = (size_t)(bb * HEADS + h);
                const unsigned short val = f2bf(acc[i][j][r]);
                if (which == 0)      Qb[(bh * NSEQ + n) * DHEAD + d] = val;
                else if (which == 1) Kb[(bh * NSEQ + n) * DHEAD + d] = val;
                else                 VTb[(bh * DHEAD + d) * NSEQ + n] = val;
            }
        }
    }
}

// ---------------------------------------------------------------------------
// MFMA GEMM 2: out = O @ w_out + b_out. A = Of bf16 [m][512], BT = WoT [n][k].
// fp32 output.
// ---------------------------------------------------------------------------
__global__ __launch_bounds__(256) void gemm_out_mfma(
    const unsigned short* __restrict__ Ab, const unsigned short* __restrict__ BT,
    const float* __restrict__ bias, float* __restrict__ C)
{
    __shared__ unsigned short As[128 * 32];
    __shared__ unsigned short Bs[128 * 32];
    const int tid = threadIdx.x, wave = tid >> 6, lane = tid & 63;
    const int l16 = lane & 15, quad = lane >> 4;
    const int m0 = blockIdx.y * 128, col0 = blockIdx.x * 128;
    const int wrow = wave >> 1, wcol = wave & 1;

    unsigned short* lA0 = As + (wave * 16) * 32;
    unsigned short* lA1 = As + (64 + wave * 16) * 32;
    unsigned short* lB0 = Bs + (wave * 16) * 32;
    unsigned short* lB1 = Bs + (64 + wave * 16) * 32;
    const unsigned short* gA = Ab + (size_t)(m0 + wave * 16 + (lane >> 2)) * DIMK + (lane & 3) * 8;
    const unsigned short* gB = BT + (size_t)(col0 + wave * 16 + (lane >> 2)) * DIMK + (lane & 3) * 8;

    f32x4 acc[4][4];
    #pragma unroll
    for (int i = 0; i < 4; ++i)
        #pragma unroll
        for (int j = 0; j < 4; ++j) acc[i][j] = (f32x4){0.f, 0.f, 0.f, 0.f};

    for (int k0 = 0; k0 < DIMK; k0 += 32) {
        __syncthreads();
        glds16(gA + k0, lA0);
        glds16(gA + (size_t)64 * DIMK + k0, lA1);
        glds16(gB + k0, lB0);
        glds16(gB + (size_t)64 * DIMK + k0, lB1);
        __syncthreads();
        bf16x8 af[4], bfr[4];
        #pragma unroll
        for (int i = 0; i < 4; ++i)
            af[i] = *(const bf16x8*)(As + (wrow * 64 + i * 16 + l16) * 32 + quad * 8);
        #pragma unroll
        for (int j = 0; j < 4; ++j)
            bfr[j] = *(const bf16x8*)(Bs + (wcol * 64 + j * 16 + l16) * 32 + quad * 8);
        #pragma unroll
        for (int i = 0; i < 4; ++i)
            #pragma unroll
            for (int j = 0; j < 4; ++j)
                acc[i][j] = __builtin_amdgcn_mfma_f32_16x16x32_bf16(af[i], bfr[j], acc[i][j], 0, 0, 0);
    }

    #pragma unroll
    for (int i = 0; i < 4; ++i) {
        #pragma unroll
        for (int r = 0; r < 4; ++r) {
            const int gr = m0 + wrow * 64 + i * 16 + quad * 4 + r;
            #pragma unroll
            for (int j = 0; j < 4; ++j) {
                const int col = col0 + wcol * 64 + j * 16 + l16;
                C[(size_t)gr * 512 + col] = acc[i][j][r] + bias[col];
            }
        }
    }
}

// ---------------------------------------------------------------------------
// Flash-style MFMA attention (unchanged from R2 except bf16 O output).
// ---------------------------------------------------------------------------
__global__ __launch_bounds__(256) void attn_mfma(
    const unsigned short* __restrict__ Qb, const unsigned short* __restrict__ Kb,
    const unsigned short* __restrict__ VTb, unsigned short* __restrict__ O)
{
    __shared__ __align__(16) unsigned short Ks[64][72];
    __shared__ __align__(16) unsigned short Vs[64][72];   // V^T tile: [d][key]
    __shared__ __align__(16) unsigned short Ps[4][16][72];

    const int tid  = threadIdx.x;
    const int wave = tid >> 6;
    const int lane = tid & 63;
    const int l16  = lane & 15;
    const int quad = lane >> 4;
    const int bh   = blockIdx.y;
    const int qw   = blockIdx.x * 64 + wave * 16;

    const unsigned short* Qg = Qb  + (size_t)bh * NSEQ * DHEAD;
    const unsigned short* Kg = Kb  + (size_t)bh * NSEQ * DHEAD;
    const unsigned short* Vg = VTb + (size_t)bh * DHEAD * NSEQ;

    bf16x8 a_q0 = *(const bf16x8*)(Qg + (size_t)(qw + l16) * DHEAD + quad * 8);
    bf16x8 a_q1 = *(const bf16x8*)(Qg + (size_t)(qw + l16) * DHEAD + 32 + quad * 8);

    f32x4 o_acc[4];
    #pragma unroll
    for (int t = 0; t < 4; ++t) o_acc[t] = (f32x4){0.f, 0.f, 0.f, 0.f};
    float m_r[4], l_r[4];
    #pragma unroll
    for (int r = 0; r < 4; ++r) { m_r[r] = -3.0e38f; l_r[r] = 0.f; }

    for (int j0 = 0; j0 < NSEQ; j0 += 64) {
        __syncthreads();
        {
            const int r  = tid >> 3;
            const int cc = (tid & 7) * 8;
            *(bf16x8*)(&Ks[r][cc])      = *(const bf16x8*)(Kg + (size_t)(j0 + r) * DHEAD + cc);
            *(bf16x8*)(&Ks[r + 32][cc]) = *(const bf16x8*)(Kg + (size_t)(j0 + r + 32) * DHEAD + cc);
            *(bf16x8*)(&Vs[r][cc])      = *(const bf16x8*)(Vg + (size_t)r * NSEQ + j0 + cc);
            *(bf16x8*)(&Vs[r + 32][cc]) = *(const bf16x8*)(Vg + (size_t)(r + 32) * NSEQ + j0 + cc);
        }
        __syncthreads();

        float sv[4][4];
        #pragma unroll
        for (int t = 0; t < 4; ++t) {
            f32x4 acc = (f32x4){0.f, 0.f, 0.f, 0.f};
            bf16x8 b0 = *(const bf16x8*)(&Ks[t * 16 + l16][quad * 8]);
            bf16x8 b1 = *(const bf16x8*)(&Ks[t * 16 + l16][32 + quad * 8]);
            acc = __builtin_amdgcn_mfma_f32_16x16x32_bf16(a_q0, b0, acc, 0, 0, 0);
            acc = __builtin_amdgcn_mfma_f32_16x16x32_bf16(a_q1, b1, acc, 0, 0, 0);
            const int col = j0 + t * 16 + l16;
            #pragma unroll
            for (int r = 0; r < 4; ++r) {
                float s = acc[r];
                if (qw + quad * 4 + r == col) s = -1.0e30f;
                sv[t][r] = s;
            }
        }

        float rmax[4];
        #pragma unroll
        for (int r = 0; r < 4; ++r)
            rmax[r] = fmaxf(fmaxf(sv[0][r], sv[1][r]), fmaxf(sv[2][r], sv[3][r]));
        #pragma unroll
        for (int off = 1; off < 16; off <<= 1)
            #pragma unroll
            for (int r = 0; r < 4; ++r)
                rmax[r] = fmaxf(rmax[r], __shfl_xor(rmax[r], off, 64));

        float rsum[4] = {0.f, 0.f, 0.f, 0.f};
        float alpha[4];
        #pragma unroll
        for (int r = 0; r < 4; ++r) {
            const float mnew = fmaxf(m_r[r], rmax[r]);
            alpha[r] = __expf(m_r[r] - mnew);
            m_r[r] = mnew;
        }
        #pragma unroll
        for (int t = 0; t < 4; ++t)
            #pragma unroll
            for (int r = 0; r < 4; ++r) {
                const float p = __expf(sv[t][r] - m_r[r]);
                sv[t][r] = p;
                rsum[r] += p;
            }
        #pragma unroll
        for (int off = 1; off < 16; off <<= 1)
            #pragma unroll
            for (int r = 0; r < 4; ++r)
                rsum[r] += __shfl_xor(rsum[r], off, 64);
        #pragma unroll
        for (int r = 0; r < 4; ++r) l_r[r] = l_r[r] * alpha[r] + rsum[r];
        #pragma unroll
        for (int t = 0; t < 4; ++t)
            #pragma unroll
            for (int r = 0; r < 4; ++r) o_acc[t][r] *= alpha[r];

        #pragma unroll
        for (int t = 0; t < 4; ++t)
            #pragma unroll
            for (int r = 0; r < 4; ++r)
                Ps[wave][quad * 4 + r][t * 16 + l16] = f2bf(sv[t][r]);
        __syncthreads();

        bf16x8 a_p0 = *(const bf16x8*)(&Ps[wave][l16][quad * 8]);
        bf16x8 a_p1 = *(const bf16x8*)(&Ps[wave][l16][32 + quad * 8]);

        #pragma unroll
        for (int t = 0; t < 4; ++t) {
            bf16x8 b0 = *(const bf16x8*)(&Vs[t * 16 + l16][quad * 8]);
            bf16x8 b1 = *(const bf16x8*)(&Vs[t * 16 + l16][32 + quad * 8]);
            o_acc[t] = __builtin_amdgcn_mfma_f32_16x16x32_bf16(a_p0, b0, o_acc[t], 0, 0, 0);
            o_acc[t] = __builtin_amdgcn_mfma_f32_16x16x32_bf16(a_p1, b1, o_acc[t], 0, 0, 0);
        }
    }

    const int bb = bh >> 3, h = bh & 7;
    #pragma unroll
    for (int r = 0; r < 4; ++r) {
        const int n = qw + quad * 4 + r;
        const float inv = 1.0f / l_r[r];
        #pragma unroll
        for (int t = 0; t < 4; ++t) {
            const int d = t * 16 + l16;
            O[((size_t)(bb * NSEQ + n)) * 512 + h * 64 + d] = f2bf(o_acc[t][r] * inv);
        }
    }
}

extern "C" void kernel_launch(void* const* d_in, const int* in_sizes, int n_in,
                              void* d_out, int out_size, void* d_ws, size_t ws_size,
                              hipStream_t stream) {
    const float* x         = (const float*)d_in[0];
    const float* w_qkv     = (const float*)d_in[1];
    const float* w_out     = (const float*)d_in[2];
    const float* b_out     = (const float*)d_in[3];
    const float* log_scale = (const float*)d_in[4];
    float* out = (float*)d_out;

    char* ws = (char*)d_ws;
    const size_t NQKV = (size_t)NB * HEADS * NSEQ * DHEAD;        // 8,388,608 elems
    unsigned short* xb  = (unsigned short*)(ws);                  // 16.8 MB
    unsigned short* Qb  = (unsigned short*)(ws + 2 * NQKV);
    unsigned short* Kb  = (unsigned short*)(ws + 4 * NQKV);
    unsigned short* VTb = (unsigned short*)(ws + 6 * NQKV);
    unsigned short* Ofb = (unsigned short*)(ws + 8 * NQKV);
    unsigned short* WqT = (unsigned short*)(ws + 10 * NQKV);      // 1.5 MB
    unsigned short* WoT = (unsigned short*)(ws + 10 * NQKV + 4 * 1024 * 1024);

    f32_to_bf16<<<M_TOT * DIMK / (256 * 8), 256, 0, stream>>>(x, xb);
    transpose_w<<<dim3(1536 / 32, 512 / 32), 256, 0, stream>>>(w_qkv, WqT, 512, 1536, log_scale, 512);
    transpose_w<<<dim3(512 / 32, 512 / 32), 256, 0, stream>>>(w_out, WoT, 512, 512, log_scale, 0);

    gemm_qkv_mfma<<<dim3(1536 / 128, M_TOT / 128), 256, 0, stream>>>(xb, WqT, Qb, Kb, VTb);

    attn_mfma<<<dim3(NSEQ / 64, NB * HEADS), 256, 0, stream>>>(Qb, Kb, VTb, Ofb);

    gemm_out_mfma<<<dim3(512 / 128, M_TOT / 128), 256, 0, stream>>>(Ofb, WoT, b_out, out);
}

// Round 4
// 284.570 us; speedup vs baseline: 51.5568x; 1.4201x over previous
//
#include <hip/hip_runtime.h>
#include <hip/hip_bf16.h>
#include <cstddef>

#define DIMK 512
#define HEADS 8
#define DHEAD 64
#define NSEQ 2048
#define NB 8
#define M_TOT (NB * NSEQ)   // 16384

typedef __attribute__((ext_vector_type(8))) short bf16x8;
typedef __attribute__((ext_vector_type(4))) float f32x4;

__device__ __forceinline__ unsigned short f2bf(float f) {
    union { float f; unsigned int u; } v; v.f = f;
    unsigned int r = v.u + 0x7fffu + ((v.u >> 16) & 1u);   // round-nearest-even
    return (unsigned short)(r >> 16);
}

// pack two fp32 -> two trunc-bf16 in one dword: hi<<16 | lo  (1 VALU op)
__device__ __forceinline__ unsigned int pk_bf_trunc(float hi, float lo) {
    union { float f; unsigned int u; } a, b; a.f = hi; b.f = lo;
    return __builtin_amdgcn_perm(a.u, b.u, 0x07060302u);
}

// async 16B/lane global->LDS. LDS dest is wave-uniform base + lane*16.
__device__ __forceinline__ void glds16(const unsigned short* g, unsigned short* l) {
    __builtin_amdgcn_global_load_lds(
        (const __attribute__((address_space(1))) void*)g,
        (__attribute__((address_space(3))) void*)l, 16, 0, 0);
}

// ---------------------------------------------------------------------------
// Pre-pass: x fp32 -> bf16 row-major [m][k]
// ---------------------------------------------------------------------------
__global__ __launch_bounds__(256) void f32_to_bf16(
    const float* __restrict__ in, unsigned short* __restrict__ out)
{
    const size_t i = ((size_t)blockIdx.x * 256 + threadIdx.x) * 8;
    const float4 a = *(const float4*)(in + i);
    const float4 b = *(const float4*)(in + i + 4);
    bf16x8 o;
    o[0] = (short)f2bf(a.x); o[1] = (short)f2bf(a.y);
    o[2] = (short)f2bf(a.z); o[3] = (short)f2bf(a.w);
    o[4] = (short)f2bf(b.x); o[5] = (short)f2bf(b.y);
    o[6] = (short)f2bf(b.z); o[7] = (short)f2bf(b.w);
    *(bf16x8*)(out + i) = o;
}

// ---------------------------------------------------------------------------
// Pre-pass: W [K][N] fp32 -> WT [N][K] bf16; rows n < nscale get *exp(log_scale).
// ---------------------------------------------------------------------------
__global__ __launch_bounds__(256) void transpose_w(
    const float* __restrict__ W, unsigned short* __restrict__ WT,
    int K, int N, const float* __restrict__ log_scale, int nscale)
{
    __shared__ float t[32][33];
    const int tx = threadIdx.x & 31, ty = threadIdx.x >> 5;
    const int k0 = blockIdx.y * 32, n0 = blockIdx.x * 32;
    #pragma unroll
    for (int s = 0; s < 32; s += 8)
        t[ty + s][tx] = W[(size_t)(k0 + ty + s) * N + n0 + tx];
    __syncthreads();
    float sc = 1.0f;
    if (n0 < nscale) sc = __expf(log_scale[0]);
    #pragma unroll
    for (int s = 0; s < 32; s += 8)
        WT[(size_t)(n0 + ty + s) * K + k0 + tx] = f2bf(t[tx][ty + s] * sc);
}

// ---------------------------------------------------------------------------
// MFMA GEMM 1 (m97 structure), epilogue scatters Q (scale folded), K, V^T.
// ---------------------------------------------------------------------------
__global__ __launch_bounds__(256) void gemm_qkv_mfma(
    const unsigned short* __restrict__ Xb, const unsigned short* __restrict__ WT,
    unsigned short* __restrict__ Qb, unsigned short* __restrict__ Kb,
    unsigned short* __restrict__ VTb)
{
    __shared__ unsigned short As[128 * 32];
    __shared__ unsigned short Bs[128 * 32];
    const int tid = threadIdx.x, wave = tid >> 6, lane = tid & 63;
    const int l16 = lane & 15, quad = lane >> 4;
    const int m0 = blockIdx.y * 128, col0 = blockIdx.x * 128;
    const int wrow = wave >> 1, wcol = wave & 1;

    unsigned short* lA0 = As + (wave * 16) * 32;
    unsigned short* lA1 = As + (64 + wave * 16) * 32;
    unsigned short* lB0 = Bs + (wave * 16) * 32;
    unsigned short* lB1 = Bs + (64 + wave * 16) * 32;
    const unsigned short* gA = Xb + (size_t)(m0 + wave * 16 + (lane >> 2)) * DIMK + (lane & 3) * 8;
    const unsigned short* gB = WT + (size_t)(col0 + wave * 16 + (lane >> 2)) * DIMK + (lane & 3) * 8;

    f32x4 acc[4][4];
    #pragma unroll
    for (int i = 0; i < 4; ++i)
        #pragma unroll
        for (int j = 0; j < 4; ++j) acc[i][j] = (f32x4){0.f, 0.f, 0.f, 0.f};

    for (int k0 = 0; k0 < DIMK; k0 += 32) {
        __syncthreads();
        glds16(gA + k0, lA0);
        glds16(gA + (size_t)64 * DIMK + k0, lA1);
        glds16(gB + k0, lB0);
        glds16(gB + (size_t)64 * DIMK + k0, lB1);
        __syncthreads();
        bf16x8 af[4], bfr[4];
        #pragma unroll
        for (int i = 0; i < 4; ++i)
            af[i] = *(const bf16x8*)(As + (wrow * 64 + i * 16 + l16) * 32 + quad * 8);
        #pragma unroll
        for (int j = 0; j < 4; ++j)
            bfr[j] = *(const bf16x8*)(Bs + (wcol * 64 + j * 16 + l16) * 32 + quad * 8);
        #pragma unroll
        for (int i = 0; i < 4; ++i)
            #pragma unroll
            for (int j = 0; j < 4; ++j)
                acc[i][j] = __builtin_amdgcn_mfma_f32_16x16x32_bf16(af[i], bfr[j], acc[i][j], 0, 0, 0);
    }

    const int which = blockIdx.x >> 2;   // 0=Q 1=K 2=V, uniform per block
    #pragma unroll
    for (int i = 0; i < 4; ++i) {
        #pragma unroll
        for (int r = 0; r < 4; ++r) {
            const int gr = m0 + wrow * 64 + i * 16 + quad * 4 + r;
            const int bb = gr >> 11, n = gr & 2047;
            #pragma unroll
            for (int j = 0; j < 4; ++j) {
                const int col = col0 + wcol * 64 + j * 16 + l16;
                const int w = col & 511, h = w >> 6, d = w & 63;
                const size_t bh = (size_t)(bb * HEADS + h);
                const unsigned short val = f2bf(acc[i][j][r]);
                if (which == 0)      Qb[(bh * NSEQ + n) * DHEAD + d] = val;
                else if (which == 1) Kb[(bh * NSEQ + n) * DHEAD + d] = val;
                else                 VTb[(bh * DHEAD + d) * NSEQ + n] = val;
            }
        }
    }
}

// ---------------------------------------------------------------------------
// MFMA GEMM 2: out = O @ w_out + b_out (fp32 output).
// ---------------------------------------------------------------------------
__global__ __launch_bounds__(256) void gemm_out_mfma(
    const unsigned short* __restrict__ Ab, const unsigned short* __restrict__ BT,
    const float* __restrict__ bias, float* __restrict__ C)
{
    __shared__ unsigned short As[128 * 32];
    __shared__ unsigned short Bs[128 * 32];
    const int tid = threadIdx.x, wave = tid >> 6, lane = tid & 63;
    const int l16 = lane & 15, quad = lane >> 4;
    const int m0 = blockIdx.y * 128, col0 = blockIdx.x * 128;
    const int wrow = wave >> 1, wcol = wave & 1;

    unsigned short* lA0 = As + (wave * 16) * 32;
    unsigned short* lA1 = As + (64 + wave * 16) * 32;
    unsigned short* lB0 = Bs + (wave * 16) * 32;
    unsigned short* lB1 = Bs + (64 + wave * 16) * 32;
    const unsigned short* gA = Ab + (size_t)(m0 + wave * 16 + (lane >> 2)) * DIMK + (lane & 3) * 8;
    const unsigned short* gB = BT + (size_t)(col0 + wave * 16 + (lane >> 2)) * DIMK + (lane & 3) * 8;

    f32x4 acc[4][4];
    #pragma unroll
    for (int i = 0; i < 4; ++i)
        #pragma unroll
        for (int j = 0; j < 4; ++j) acc[i][j] = (f32x4){0.f, 0.f, 0.f, 0.f};

    for (int k0 = 0; k0 < DIMK; k0 += 32) {
        __syncthreads();
        glds16(gA + k0, lA0);
        glds16(gA + (size_t)64 * DIMK + k0, lA1);
        glds16(gB + k0, lB0);
        glds16(gB + (size_t)64 * DIMK + k0, lB1);
        __syncthreads();
        bf16x8 af[4], bfr[4];
        #pragma unroll
        for (int i = 0; i < 4; ++i)
            af[i] = *(const bf16x8*)(As + (wrow * 64 + i * 16 + l16) * 32 + quad * 8);
        #pragma unroll
        for (int j = 0; j < 4; ++j)
            bfr[j] = *(const bf16x8*)(Bs + (wcol * 64 + j * 16 + l16) * 32 + quad * 8);
        #pragma unroll
        for (int i = 0; i < 4; ++i)
            #pragma unroll
            for (int j = 0; j < 4; ++j)
                acc[i][j] = __builtin_amdgcn_mfma_f32_16x16x32_bf16(af[i], bfr[j], acc[i][j], 0, 0, 0);
    }

    #pragma unroll
    for (int i = 0; i < 4; ++i) {
        #pragma unroll
        for (int r = 0; r < 4; ++r) {
            const int gr = m0 + wrow * 64 + i * 16 + quad * 4 + r;
            #pragma unroll
            for (int j = 0; j < 4; ++j) {
                const int col = col0 + wcol * 64 + j * 16 + l16;
                C[(size_t)gr * 512 + col] = acc[i][j][r] + bias[col];
            }
        }
    }
}

// ---------------------------------------------------------------------------
// Flash attention v2: S^T orientation, fixed-max softmax, deferred row-sum,
// glds staging into m97-style [row][32-short] half-tiles, hoisted diag mask.
// Wave owns 16 query rows; block = 4 waves = 64 rows; loop over 64-key tiles.
//   S^T tile t: D[m=key(t*16+quad*4+r)][n=qrow(l16)] = K·Q^T
//   P^T packed (trunc bf16) -> wave-private Pq[l16-qrow][64-key] rows
//   O^T  : D[m=d(t*16+quad*4+r)][n=qrow(l16)] += V^T·P^T
// ---------------------------------------------------------------------------
__global__ __launch_bounds__(256) void attn_mfma(
    const unsigned short* __restrict__ Qb, const unsigned short* __restrict__ Kb,
    const unsigned short* __restrict__ VTb, unsigned short* __restrict__ O)
{
    __shared__ unsigned short Ks0[64 * 32];   // K keys x d[0:32)
    __shared__ unsigned short Ks1[64 * 32];   // K keys x d[32:64)
    __shared__ unsigned short Vs0[64 * 32];   // V^T d x keys[0:32)
    __shared__ unsigned short Vs1[64 * 32];   // V^T d x keys[32:64)
    __shared__ __align__(16) unsigned short Pq[4][16][72];   // per-wave P[qrow][key]

    const int tid  = threadIdx.x;
    const int wave = tid >> 6;
    const int lane = tid & 63;
    const int l16  = lane & 15;
    const int quad = lane >> 4;
    const int bh   = blockIdx.y;
    const int qw   = blockIdx.x * 64 + wave * 16;

    const unsigned short* Qg = Qb  + (size_t)bh * NSEQ * DHEAD;
    const unsigned short* Kg = Kb  + (size_t)bh * NSEQ * DHEAD;
    const unsigned short* Vg = VTb + (size_t)bh * DHEAD * NSEQ;

    // Q B-fragments (B[k=d quad*8+j][n=qrow l16]), resident all kernel
    const bf16x8 b_q0 = *(const bf16x8*)(Qg + (size_t)(qw + l16) * DHEAD + quad * 8);
    const bf16x8 b_q1 = *(const bf16x8*)(Qg + (size_t)(qw + l16) * DHEAD + 32 + quad * 8);

    // glds source pointers (16B/lane)
    const int srow  = wave * 16 + (lane >> 2);
    const int scol8 = (lane & 3) * 8;
    const unsigned short* gK = Kg + (size_t)srow * DHEAD + scol8;
    const unsigned short* gV = Vg + (size_t)srow * NSEQ + scol8;
    unsigned short* lK0 = Ks0 + wave * 512;
    unsigned short* lK1 = Ks1 + wave * 512;
    unsigned short* lV0 = Vs0 + wave * 512;
    unsigned short* lV1 = Vs1 + wave * 512;

    f32x4 o_acc[4];
    #pragma unroll
    for (int t = 0; t < 4; ++t) o_acc[t] = (f32x4){0.f, 0.f, 0.f, 0.f};
    float lsum = 0.f;
    const int diag_j0 = blockIdx.x * 64;

    for (int j0 = 0; j0 < NSEQ; j0 += 64) {
        __syncthreads();   // prev-iter frag reads done
        glds16(gK + (size_t)j0 * DHEAD, lK0);
        glds16(gK + (size_t)j0 * DHEAD + 32, lK1);
        glds16(gV + j0, lV0);
        glds16(gV + j0 + 32, lV1);
        __syncthreads();   // tiles staged (vmcnt drained by barrier)

        // ---- S^T = K Q^T, then p = exp(s) ----
        float p[4][4];
        #pragma unroll
        for (int t = 0; t < 4; ++t) {
            const bf16x8 a0 = *(const bf16x8*)(Ks0 + (t * 16 + l16) * 32 + quad * 8);
            const bf16x8 a1 = *(const bf16x8*)(Ks1 + (t * 16 + l16) * 32 + quad * 8);
            f32x4 acc = (f32x4){0.f, 0.f, 0.f, 0.f};
            acc = __builtin_amdgcn_mfma_f32_16x16x32_bf16(a0, b_q0, acc, 0, 0, 0);
            acc = __builtin_amdgcn_mfma_f32_16x16x32_bf16(a1, b_q1, acc, 0, 0, 0);
            #pragma unroll
            for (int r = 0; r < 4; ++r) p[t][r] = __expf(acc[r]);
        }

        // ---- self-token mask: only the diagonal tile (wave-uniform branch) ----
        if (j0 == diag_j0) {
            #pragma unroll
            for (int t = 0; t < 4; ++t)
                if (t == wave)
                    #pragma unroll
                    for (int r = 0; r < 4; ++r)
                        if (l16 == quad * 4 + r) p[t][r] = 0.f;
        }

        // ---- deferred row-sum partials ----
        #pragma unroll
        for (int t = 0; t < 4; ++t)
            #pragma unroll
            for (int r = 0; r < 4; ++r) lsum += p[t][r];

        // ---- P^T -> wave-private LDS (packed trunc bf16, b64 writes) ----
        #pragma unroll
        for (int t = 0; t < 4; ++t) {
            uint2 w;
            w.x = pk_bf_trunc(p[t][1], p[t][0]);
            w.y = pk_bf_trunc(p[t][3], p[t][2]);
            *(uint2*)(&Pq[wave][l16][t * 16 + quad * 4]) = w;
        }
        __builtin_amdgcn_wave_barrier();   // wave-private: no __syncthreads needed

        const bf16x8 b_p0 = *(const bf16x8*)(&Pq[wave][l16][quad * 8]);
        const bf16x8 b_p1 = *(const bf16x8*)(&Pq[wave][l16][32 + quad * 8]);

        // ---- O^T += V^T P^T ----
        #pragma unroll
        for (int t = 0; t < 4; ++t) {
            const bf16x8 a0 = *(const bf16x8*)(Vs0 + (t * 16 + l16) * 32 + quad * 8);
            const bf16x8 a1 = *(const bf16x8*)(Vs1 + (t * 16 + l16) * 32 + quad * 8);
            o_acc[t] = __builtin_amdgcn_mfma_f32_16x16x32_bf16(a0, b_p0, o_acc[t], 0, 0, 0);
            o_acc[t] = __builtin_amdgcn_mfma_f32_16x16x32_bf16(a1, b_p1, o_acc[t], 0, 0, 0);
        }
    }

    // ---- epilogue: reduce l over the 4 quads of each qrow, write O bf16 ----
    lsum += __shfl_xor(lsum, 16, 64);
    lsum += __shfl_xor(lsum, 32, 64);
    const float inv = 1.0f / lsum;
    const int bb = bh >> 3, h = bh & 7;
    const int n = qw + l16;
    unsigned short* Orow = O + ((size_t)(bb * NSEQ + n)) * 512 + h * 64;
    #pragma unroll
    for (int t = 0; t < 4; ++t) {
        ushort4 o4;
        o4.x = f2bf(o_acc[t][0] * inv);
        o4.y = f2bf(o_acc[t][1] * inv);
        o4.z = f2bf(o_acc[t][2] * inv);
        o4.w = f2bf(o_acc[t][3] * inv);
        *(ushort4*)(Orow + t * 16 + quad * 4) = o4;
    }
}

extern "C" void kernel_launch(void* const* d_in, const int* in_sizes, int n_in,
                              void* d_out, int out_size, void* d_ws, size_t ws_size,
                              hipStream_t stream) {
    const float* x         = (const float*)d_in[0];
    const float* w_qkv     = (const float*)d_in[1];
    const float* w_out     = (const float*)d_in[2];
    const float* b_out     = (const float*)d_in[3];
    const float* log_scale = (const float*)d_in[4];
    float* out = (float*)d_out;

    char* ws = (char*)d_ws;
    const size_t NQKV = (size_t)NB * HEADS * NSEQ * DHEAD;        // 8,388,608 elems
    unsigned short* xb  = (unsigned short*)(ws);
    unsigned short* Qb  = (unsigned short*)(ws + 2 * NQKV);
    unsigned short* Kb  = (unsigned short*)(ws + 4 * NQKV);
    unsigned short* VTb = (unsigned short*)(ws + 6 * NQKV);
    unsigned short* Ofb = (unsigned short*)(ws + 8 * NQKV);
    unsigned short* WqT = (unsigned short*)(ws + 10 * NQKV);
    unsigned short* WoT = (unsigned short*)(ws + 10 * NQKV + 4 * 1024 * 1024);

    f32_to_bf16<<<M_TOT * DIMK / (256 * 8), 256, 0, stream>>>(x, xb);
    transpose_w<<<dim3(1536 / 32, 512 / 32), 256, 0, stream>>>(w_qkv, WqT, 512, 1536, log_scale, 512);
    transpose_w<<<dim3(512 / 32, 512 / 32), 256, 0, stream>>>(w_out, WoT, 512, 512, log_scale, 0);

    gemm_qkv_mfma<<<dim3(1536 / 128, M_TOT / 128), 256, 0, stream>>>(xb, WqT, Qb, Kb, VTb);

    attn_mfma<<<dim3(NSEQ / 64, NB * HEADS), 256, 0, stream>>>(Qb, Kb, VTb, Ofb);

    gemm_out_mfma<<<dim3(512 / 128, M_TOT / 128), 256, 0, stream>>>(Ofb, WoT, b_out, out);
}